// Round 9
// baseline (1761.691 us; speedup 1.0000x reference)
//
#include <hip/hip_runtime.h>
#include <hip/hip_bf16.h>
#include <math.h>

#define NTH 256

typedef __bf16 bf16x8 __attribute__((ext_vector_type(8)));
typedef float  f32x4  __attribute__((ext_vector_type(4)));
typedef unsigned short ushort;
typedef ushort u16x8 __attribute__((ext_vector_type(8)));

__device__ __forceinline__ ushort f2bf(float x){
    union { float f; unsigned int u; } v; v.f = x;
    unsigned int r = v.u + 0x7fffu + ((v.u >> 16) & 1u);
    return (ushort)(r >> 16);
}
__device__ __forceinline__ float bf2f(ushort h){
    union { unsigned int u; float f; } v; v.u = ((unsigned int)h) << 16;
    return v.f;
}

// ============================ prep kernels ============================
__global__ void prep_combined_bf(const float* __restrict__ Wq, const float* __restrict__ Wk,
                                 const float* __restrict__ Wv, const float* __restrict__ in_w,
                                 ushort* __restrict__ dh)
{
    int o = blockIdx.x*NTH + threadIdx.x;
    if (o >= 76800) return;
    int c = o/160, j = o - c*160;
    const float* Wsel = (c<160) ? Wq : (c<320) ? Wk : Wv;
    const float* wrow = Wsel + j*160;
    const float* irow = in_w + c*160;
    float s = 0.f;
    for (int k=0;k<160;k++) s = fmaf(wrow[k], irow[k], s);
    dh[o] = f2bf(s);
}

__global__ void prep_H_bf(const float* __restrict__ f_in_w, const float* __restrict__ out_w,
                          ushort* __restrict__ dh)
{
    int o = blockIdx.x*NTH + threadIdx.x;
    if (o >= 76800) return;
    int n = o/160, k = o - n*160;
    float s = 0.f;
    for (int c=0;c<160;c++) s = fmaf(f_in_w[n*160+c], out_w[c*160+k], s);
    dh[o] = f2bf(s);
}

__global__ void prep_cvec(const float* __restrict__ f_in_w, const float* __restrict__ out_b,
                          const float* __restrict__ f_in_b, float* __restrict__ cv)
{
    int n = blockIdx.x*NTH + threadIdx.x;
    if (n >= 480) return;
    float s = f_in_b[n];
    for (int c=0;c<160;c++) s = fmaf(f_in_w[n*160+c], out_b[c], s);
    cv[n] = s;
}

__global__ void prep_conv_bf1(const float* __restrict__ src, ushort* __restrict__ dh, int n)
{
    int o = blockIdx.x*NTH + threadIdx.x;
    if (o >= n) return;
    dh[o] = f2bf(src[o]);
}

__global__ void prep_conv_bf2(const float* __restrict__ src,
                              ushort* __restrict__ dh, ushort* __restrict__ dl, int n)
{
    int o = blockIdx.x*NTH + threadIdx.x;
    if (o >= n) return;
    float s = src[o];
    ushort h = f2bf(s);
    dh[o] = h; dl[o] = f2bf(s - bf2f(h));
}

// ============================ MFMA GEMM (fp32 A, split-x3) — final linear ============
__global__ __launch_bounds__(NTH)
void gemm_mfma_lin(const float* __restrict__ A,
                   const ushort* __restrict__ Wh, const ushort* __restrict__ Wl,
                   const float* __restrict__ bias, float* __restrict__ C, int N)
{
    __shared__ ushort sAh[128*40], sAl[128*40];
    __shared__ ushort sWh[160*40], sWl[160*40];

    const int tid = threadIdx.x;
    const int lane = tid & 63, wave = tid >> 6;
    const int wm = wave >> 1, wn = wave & 1;
    const int ln = lane & 15, g = lane >> 4;
    const long m0 = (long)blockIdx.x * 128;
    const int  n0 = blockIdx.y * 160;

    f32x4 acc[4][5];
#pragma unroll
    for (int mt=0;mt<4;mt++)
#pragma unroll
        for (int nt=0;nt<5;nt++)
#pragma unroll
            for (int r=0;r<4;r++) acc[mt][nt][r] = 0.f;

    for (int k0=0;k0<160;k0+=32){
#pragma unroll
        for (int i=0;i<4;i++){
            int f = tid + 256*i;
            int m = f >> 3, seg = f & 7;
            float4 v = *(const float4*)(A + (m0+m)*160 + k0 + seg*4);
            ushort4 hv, lv;
            hv.x = f2bf(v.x); lv.x = f2bf(v.x - bf2f(hv.x));
            hv.y = f2bf(v.y); lv.y = f2bf(v.y - bf2f(hv.y));
            hv.z = f2bf(v.z); lv.z = f2bf(v.z - bf2f(hv.z));
            hv.w = f2bf(v.w); lv.w = f2bf(v.w - bf2f(hv.w));
            *(ushort4*)(sAh + m*40 + seg*4) = hv;
            *(ushort4*)(sAl + m*40 + seg*4) = lv;
        }
#pragma unroll
        for (int i=0;i<5;i++){
            int e = tid + 256*i;
            int pl = (e >= 640);
            int idx = pl ? e-640 : e;
            int n = idx >> 2, seg = idx & 3;
            const ushort* src = (pl ? Wl : Wh) + (long)(n0+n)*160 + k0 + seg*8;
            ushort* dst = (pl ? sWl : sWh) + n*40 + seg*8;
            *(uint4*)dst = *(const uint4*)src;
        }
        __syncthreads();

        bf16x8 ah[4], al[4];
#pragma unroll
        for (int mt=0;mt<4;mt++){
            int off = (wm*64 + mt*16 + ln)*40 + g*8;
            ah[mt] = *(const bf16x8*)(sAh + off);
            al[mt] = *(const bf16x8*)(sAl + off);
        }
#pragma unroll
        for (int nt=0;nt<5;nt++){
            int offw = (wn*80 + nt*16 + ln)*40 + g*8;
            bf16x8 bh = *(const bf16x8*)(sWh + offw);
            bf16x8 bl = *(const bf16x8*)(sWl + offw);
#pragma unroll
            for (int mt=0;mt<4;mt++){
                acc[mt][nt] = __builtin_amdgcn_mfma_f32_16x16x32_bf16(ah[mt], bh, acc[mt][nt], 0,0,0);
                acc[mt][nt] = __builtin_amdgcn_mfma_f32_16x16x32_bf16(al[mt], bh, acc[mt][nt], 0,0,0);
                acc[mt][nt] = __builtin_amdgcn_mfma_f32_16x16x32_bf16(ah[mt], bl, acc[mt][nt], 0,0,0);
            }
        }
        __syncthreads();
    }

#pragma unroll
    for (int nt=0;nt<5;nt++){
        int col = n0 + wn*80 + nt*16 + ln;
        float bv = bias[col];
#pragma unroll
        for (int mt=0;mt<4;mt++){
#pragma unroll
            for (int r=0;r<4;r++){
                long row = m0 + wm*64 + mt*16 + g*4 + r;
                float x = acc[mt][nt][r] + bv;
                x = x > 0.f ? x : expm1f(x);
                C[row*N + col] = x;
            }
        }
    }
}

// ============================ bf16 GEMM (A bf16, W single-plane) ============
// C(M x N) = A(M x 160, bf16) @ W(N x 160, bf16)^T + bias -> bf16.
__global__ __launch_bounds__(NTH)
void gemm_bf(const ushort* __restrict__ A0, const ushort* __restrict__ A1,
             const ushort* __restrict__ Wh0, const ushort* __restrict__ Wh1,
             const float* __restrict__ b0, const float* __restrict__ b1,
             ushort* __restrict__ C0, ushort* __restrict__ C1, int N)
{
    const int z = blockIdx.z;
    const ushort* A  = z ? A1 : A0;
    const ushort* Wh = z ? Wh1 : Wh0;
    const float* bias = z ? b1 : b0;
    ushort* C = z ? C1 : C0;

    __shared__ ushort sA[128*40];
    __shared__ ushort sW[160*40];

    const int tid = threadIdx.x;
    const int lane = tid & 63, wave = tid >> 6;
    const int wm = wave >> 1, wn = wave & 1;
    const int ln = lane & 15, g = lane >> 4;
    const long m0 = (long)blockIdx.x * 128;
    const int  n0 = blockIdx.y * 160;

    f32x4 acc[4][5];
#pragma unroll
    for (int mt=0;mt<4;mt++)
#pragma unroll
        for (int nt=0;nt<5;nt++)
#pragma unroll
            for (int r=0;r<4;r++) acc[mt][nt][r] = 0.f;

    for (int k0=0;k0<160;k0+=32){
#pragma unroll
        for (int i=0;i<2;i++){
            int e = tid + 256*i;
            int m = e >> 2, seg = e & 3;
            *(uint4*)(sA + m*40 + seg*8) =
                *(const uint4*)(A + (m0+m)*160 + k0 + seg*8);
        }
#pragma unroll
        for (int i=0;i<3;i++){
            int e = tid + 256*i;
            if (e < 640){
                int n = e >> 2, seg = e & 3;
                *(uint4*)(sW + n*40 + seg*8) =
                    *(const uint4*)(Wh + (long)(n0+n)*160 + k0 + seg*8);
            }
        }
        __syncthreads();

        bf16x8 af[4];
#pragma unroll
        for (int mt=0;mt<4;mt++)
            af[mt] = *(const bf16x8*)(sA + (wm*64 + mt*16 + ln)*40 + g*8);
#pragma unroll
        for (int nt=0;nt<5;nt++){
            bf16x8 bh = *(const bf16x8*)(sW + (wn*80 + nt*16 + ln)*40 + g*8);
#pragma unroll
            for (int mt=0;mt<4;mt++)
                acc[mt][nt] = __builtin_amdgcn_mfma_f32_16x16x32_bf16(af[mt], bh, acc[mt][nt], 0,0,0);
        }
        __syncthreads();
    }

#pragma unroll
    for (int nt=0;nt<5;nt++){
        int col = n0 + wn*80 + nt*16 + ln;
        float bv = bias[col];
#pragma unroll
        for (int mt=0;mt<4;mt++){
#pragma unroll
            for (int r=0;r<4;r++){
                long row = m0 + wm*64 + mt*16 + g*4 + r;
                C[row*N + col] = f2bf(acc[mt][nt][r] + bv);
            }
        }
    }
}

// ============================ MFMA attention, layers 1/2 ============
// One wave per node. Q read direct from global (L2); K staged row-major;
// V staged TRANSPOSED in LDS so PV B-frags are ds_read_b128.
__global__ __launch_bounds__(64)
void attn_layer_mfma(const ushort* __restrict__ XPi, const ushort* __restrict__ XPo,
                     const int* __restrict__ in_idx, const int* __restrict__ out_idx,
                     ushort* __restrict__ Oi, ushort* __restrict__ Oo, int node_base)
{
    const ushort* XP = blockIdx.y ? XPo : XPi;
    const int*  idx  = blockIdx.y ? out_idx : in_idx;
    ushort* O        = blockIdx.y ? Oo : Oi;

    __shared__ ushort sK[16*168];      // K rows (cols 160..319)
    __shared__ ushort sVT[160*24];     // V transposed [col][k], k<16
    __shared__ ushort Pall[5*16*24];

    const int lane = threadIdx.x;
    const int ln = lane & 15, q = lane >> 4;
    const int node = node_base + blockIdx.x;
    const int bb = node >> 12, nn = node & 4095;

    int idxv = nn;
    if (lane >= 1 && lane < 16) idxv = idx[(long)node*15 + lane-1];

    const int rowq = __shfl(idxv, ln);
    const ushort* qptr = XP + (long)(bb*4096 + rowq)*480;   // Q B-frag base

    // gather K+V: 16 rows x 40 uint4 (cols 160..479); V transposed on the fly
#pragma unroll
    for (int i=0;i<10;i++){
        int e = lane + 64*i;
        int r = e/40, c = e - r*40;
        int rowg = __shfl(idxv, r);
        uint4 v = *(const uint4*)(XP + (long)(bb*4096 + rowg)*480 + 160 + c*8);
        if (c < 20){
            *(uint4*)(sK + r*168 + c*8) = v;
        } else {
            int vc = (c-20)*8;
            const ushort* pv = (const ushort*)&v;
#pragma unroll
            for (int jj=0;jj<8;jj++) sVT[(vc+jj)*24 + r] = pv[jj];
        }
    }
    __syncthreads();

    const float scale = 0.17677669529663687f;
#pragma unroll
    for (int h=0;h<5;h++){
        // S^T = K @ Q^T : A=K (LDS), B=Q (global 16B/lane)
        bf16x8 ka = *(const bf16x8*)(sK + ln*168 + h*32 + q*8);
        bf16x8 qb = *(const bf16x8*)(qptr + h*32 + q*8);
        f32x4 s = {0.f,0.f,0.f,0.f};
        s = __builtin_amdgcn_mfma_f32_16x16x32_bf16(ka, qb, s, 0,0,0);
        float x[4], m = -1e30f;
#pragma unroll
        for (int r=0;r<4;r++){ x[r] = s[r]*scale; m = fmaxf(m, x[r]); }
        m = fmaxf(m, __shfl_xor(m, 16));
        m = fmaxf(m, __shfl_xor(m, 32));
        float e0[4], sum = 0.f;
#pragma unroll
        for (int r=0;r<4;r++){ e0[r] = __expf(x[r]-m); sum += e0[r]; }
        sum += __shfl_xor(sum, 16);
        sum += __shfl_xor(sum, 32);
        float inv = 1.f/sum;
        ushort4 pw;
        pw.x = f2bf(e0[0]*inv); pw.y = f2bf(e0[1]*inv);
        pw.z = f2bf(e0[2]*inv); pw.w = f2bf(e0[3]*inv);
        *(ushort4*)(Pall + h*384 + ln*24 + q*4) = pw;
    }
    __syncthreads();

#pragma unroll
    for (int h=0;h<5;h++){
        u16x8 ta;
#pragma unroll
        for (int jj=0;jj<8;jj++) ta[jj] = 0;
        if (q < 2) ta = *(const u16x8*)(Pall + h*384 + ln*24 + q*8);
        bf16x8 ap = *(bf16x8*)&ta;
#pragma unroll
        for (int half=0; half<2; half++){
            u16x8 tb;
#pragma unroll
            for (int jj=0;jj<8;jj++) tb[jj] = 0;
            if (q < 2)
                tb = *(const u16x8*)(sVT + (h*32 + half*16 + ln)*24 + q*8);
            bf16x8 bv = *(bf16x8*)&tb;
            f32x4 o = {0.f,0.f,0.f,0.f};
            o = __builtin_amdgcn_mfma_f32_16x16x32_bf16(ap, bv, o, 0,0,0);
#pragma unroll
            for (int r=0;r<4;r++)
                O[(long)(blockIdx.x*16 + q*4 + r)*160 + h*32 + half*16 + ln] = f2bf(o[r]);
        }
    }
}

// ============================ MFMA final attention ============
// One wave per node. Stage fk|fv once (cols 160..479); fq B-frags direct global.
__global__ __launch_bounds__(64)
void attn_final_mfma(const ushort* __restrict__ FQi, const ushort* __restrict__ FQo,
                     ushort* __restrict__ O2)
{
    __shared__ ushort F[32*328];       // cols 160..479: fk @0, fv @160
    __shared__ ushort P[32*40];

    const int lane = threadIdx.x;
    const int ln = lane & 15, q = lane >> 4;
    const int nl = blockIdx.x;

#pragma unroll
    for (int i=0;i<20;i++){
        int e = lane + 64*i;
        int r = e/40, c = e - r*40;
        const ushort* src = (r<16) ? (FQi + (long)(nl*16+r)*480 + 160 + c*8)
                                   : (FQo + (long)(nl*16+r-16)*480 + 160 + c*8);
        *(uint4*)(F + r*328 + c*8) = *(const uint4*)src;
    }
    __syncthreads();

    // S2^T: A = fk (LDS), B = fq (global)
    f32x4 sc[2][2];
#pragma unroll
    for (int ti=0;ti<2;ti++)
#pragma unroll
        for (int tj=0;tj<2;tj++){
            f32x4 a = {0.f,0.f,0.f,0.f};
            const ushort* qsrc = ti ? (FQo + (long)(nl*16+ln)*480)
                                    : (FQi + (long)(nl*16+ln)*480);
#pragma unroll
            for (int kc=0;kc<5;kc++){
                bf16x8 ka = *(const bf16x8*)(F + (tj*16+ln)*328 + kc*32 + q*8);
                bf16x8 qb = *(const bf16x8*)(qsrc + kc*32 + q*8);
                a = __builtin_amdgcn_mfma_f32_16x16x32_bf16(ka, qb, a, 0,0,0);
            }
            sc[ti][tj] = a;
        }

    const float scale = 0.07905694150420949f;
#pragma unroll
    for (int ti=0;ti<2;ti++){
        float x[2][4], m = -1e30f;
#pragma unroll
        for (int tj=0;tj<2;tj++)
#pragma unroll
            for (int r=0;r<4;r++){ x[tj][r] = sc[ti][tj][r]*scale; m = fmaxf(m, x[tj][r]); }
        m = fmaxf(m, __shfl_xor(m, 16));
        m = fmaxf(m, __shfl_xor(m, 32));
        float sum = 0.f;
#pragma unroll
        for (int tj=0;tj<2;tj++)
#pragma unroll
            for (int r=0;r<4;r++){ x[tj][r] = __expf(x[tj][r]-m); sum += x[tj][r]; }
        sum += __shfl_xor(sum, 16);
        sum += __shfl_xor(sum, 32);
        float inv = 1.f/sum;
#pragma unroll
        for (int tj=0;tj<2;tj++){
            ushort4 pw;
            pw.x = f2bf(x[tj][0]*inv); pw.y = f2bf(x[tj][1]*inv);
            pw.z = f2bf(x[tj][2]*inv); pw.w = f2bf(x[tj][3]*inv);
            *(ushort4*)(P + (ti*16+ln)*40 + tj*16 + q*4) = pw;
        }
    }
    __syncthreads();

    bf16x8 ap[2];
#pragma unroll
    for (int mi=0;mi<2;mi++)
        ap[mi] = *(const bf16x8*)(P + (mi*16+ln)*40 + q*8);
#pragma unroll
    for (int nt=0;nt<10;nt++){
        u16x8 tb;
#pragma unroll
        for (int jj=0;jj<8;jj++) tb[jj] = F[(q*8+jj)*328 + 160 + nt*16 + ln];
        bf16x8 bv = *(bf16x8*)&tb;
#pragma unroll
        for (int mi=0;mi<2;mi++){
            f32x4 o = {0.f,0.f,0.f,0.f};
            o = __builtin_amdgcn_mfma_f32_16x16x32_bf16(ap[mi], bv, o, 0,0,0);
#pragma unroll
            for (int r=0;r<4;r++)
                O2[(long)(nl*32 + mi*16 + q*4 + r)*160 + nt*16 + ln] = f2bf(o[r]);
        }
    }
}

// ============================ flipped O3 GEMM + max-pool ============
// D = fo @ O2^T per node: A = fo (LDS-resident, one barrier), B = O2 rows
// straight from global. Pool over n (rows) via in-reg max + ln-shuffles.
__global__ __launch_bounds__(NTH)
void gemm_o3pool(const ushort* __restrict__ O2, const ushort* __restrict__ fo,
                 const float* __restrict__ fb, float* __restrict__ pooled,
                 int node_base)
{
    __shared__ ushort sW[160*168];     // fo [col][k]

    const int tid = threadIdx.x;
    const int lane = tid & 63, wave = tid >> 6;
    const int ln = lane & 15, q = lane >> 4;

#pragma unroll
    for (int i=0;i<13;i++){
        int e = tid + 256*i;
        if (e < 3200){
            int nr = e/20, c = e - nr*20;
            *(uint4*)(sW + nr*168 + c*8) = *(const uint4*)(fo + nr*160 + c*8);
        }
    }
    __syncthreads();

    const int node_l = blockIdx.x*4 + wave;
    const ushort* b2 = O2 + (long)node_l*5120;     // 32x160 rows

    f32x4 acc[10][2];
#pragma unroll
    for (int mt=0;mt<10;mt++)
#pragma unroll
        for (int nt=0;nt<2;nt++)
#pragma unroll
            for (int r=0;r<4;r++) acc[mt][nt][r] = 0.f;

#pragma unroll
    for (int kc=0;kc<5;kc++){
        bf16x8 bfr[2];
#pragma unroll
        for (int nt=0;nt<2;nt++)
            bfr[nt] = *(const bf16x8*)(b2 + (nt*16+ln)*160 + kc*32 + q*8);
#pragma unroll
        for (int mt=0;mt<10;mt++){
            bf16x8 af = *(const bf16x8*)(sW + (mt*16+ln)*168 + kc*32 + q*8);
#pragma unroll
            for (int nt=0;nt<2;nt++)
                acc[mt][nt] = __builtin_amdgcn_mfma_f32_16x16x32_bf16(af, bfr[nt], acc[mt][nt], 0,0,0);
        }
    }

    const int node = node_base + node_l;
#pragma unroll
    for (int mt=0;mt<10;mt++){
#pragma unroll
        for (int r=0;r<4;r++){
            float v = fmaxf(acc[mt][0][r], acc[mt][1][r]);
            v = fmaxf(v, __shfl_xor(v, 1));
            v = fmaxf(v, __shfl_xor(v, 2));
            v = fmaxf(v, __shfl_xor(v, 4));
            v = fmaxf(v, __shfl_xor(v, 8));
            if (ln == 0){
                int col = mt*16 + q*4 + r;
                pooled[(long)node*160 + col] = v + fb[col];
            }
        }
    }
}

// ============================ host ============================
extern "C" void kernel_launch(void* const* d_in, const int* in_sizes, int n_in,
                              void* d_out, int out_size, void* d_ws, size_t ws_size,
                              hipStream_t stream)
{
    const float* X       = (const float*)d_in[0];
    const int*   in_idx  = (const int*)  d_in[1];
    const int*   out_idx = (const int*)  d_in[2];
    const float* iWq     = (const float*)d_in[3];
    const float* iWk     = (const float*)d_in[4];
    const float* iWv     = (const float*)d_in[5];
    const float* i_in_w  = (const float*)d_in[6];
    const float* i_in_b  = (const float*)d_in[7];
    const float* i_out_w = (const float*)d_in[8];
    const float* i_out_b = (const float*)d_in[9];
    const float* oWq     = (const float*)d_in[10];
    const float* oWk     = (const float*)d_in[11];
    const float* oWv     = (const float*)d_in[12];
    const float* o_in_w  = (const float*)d_in[13];
    const float* o_in_b  = (const float*)d_in[14];
    const float* o_out_w = (const float*)d_in[15];
    const float* o_out_b = (const float*)d_in[16];
    const float* f_in_w  = (const float*)d_in[17];
    const float* f_in_b  = (const float*)d_in[18];
    const float* f_out_w = (const float*)d_in[19];
    const float* f_out_b = (const float*)d_in[20];
    const float* lin_w   = (const float*)d_in[21];
    const float* lin_b   = (const float*)d_in[22];

    float* ws = (float*)d_ws;
    float* pooled = ws;                           // 32768*160 fp32
    float* c_i    = pooled + 5242880;             // 480
    float* c_o    = c_i + 480;
    ushort* ub    = (ushort*)(c_o + 480);
    ushort* Xb    = ub;                           // 32768*160 bf16
    ushort* XPb_i = Xb + 5242880;                 // 32768*480 bf16
    ushort* XPb_o = XPb_i + 15728640;
    ushort* Wci_h = XPb_o + 15728640;             // 76800 each
    ushort* Wco_h = Wci_h + 76800;
    ushort* Hi_h  = Wco_h + 76800;
    ushort* Ho_h  = Hi_h  + 76800;
    ushort* fo_h  = Ho_h  + 76800;                // 25600 each
    ushort* li_h  = fo_h  + 25600;
    ushort* li_l  = li_h  + 25600;
    ushort* sb_us = li_l + 25600;
    const unsigned long long fixed = 23785920ULL;   // floats

    size_t avail = ws_size / 4;
    int ns = 4096;
    while (ns > 64 && fixed + 12800ULL*ns > avail) ns >>= 1;

    ushort* O_i = sb_us;                          // ns*16*160
    ushort* O_o = O_i + (size_t)2560*ns;
    ushort* FQi = O_o + (size_t)2560*ns;          // ns*16*480
    ushort* FQo = FQi + (size_t)7680*ns;
    ushort* O2  = FQo + (size_t)7680*ns;          // ns*32*160

    prep_combined_bf<<<300,NTH,0,stream>>>(iWq,iWk,iWv,i_in_w, Wci_h);
    prep_combined_bf<<<300,NTH,0,stream>>>(oWq,oWk,oWv,o_in_w, Wco_h);
    prep_H_bf<<<300,NTH,0,stream>>>(f_in_w, i_out_w, Hi_h);
    prep_H_bf<<<300,NTH,0,stream>>>(f_in_w, o_out_w, Ho_h);
    prep_cvec<<<2,NTH,0,stream>>>(f_in_w, i_out_b, f_in_b, c_i);
    prep_cvec<<<2,NTH,0,stream>>>(f_in_w, o_out_b, f_in_b, c_o);
    prep_conv_bf1<<<100,NTH,0,stream>>>(f_out_w, fo_h, 25600);
    prep_conv_bf2<<<100,NTH,0,stream>>>(lin_w,   li_h, li_l, 25600);
    prep_conv_bf1<<<20480,NTH,0,stream>>>(X, Xb, 5242880);

    // XP = Xb @ Wc^T + in_b  -> bf16 (both layers via z)
    dim3 g1(256, 3, 2);
    gemm_bf<<<g1,NTH,0,stream>>>(Xb, Xb, Wci_h, Wco_h, i_in_b, o_in_b,
                                 XPb_i, XPb_o, 480);

    int S = 32768 / ns;
    for (int s=0;s<S;s++){
        int base = s*ns;
        dim3 ga(ns, 2);
        attn_layer_mfma<<<ga,64,0,stream>>>(XPb_i, XPb_o, in_idx, out_idx, O_i, O_o, base);
        dim3 g3(ns/8, 3, 2);
        gemm_bf<<<g3,NTH,0,stream>>>(O_i, O_o, Hi_h, Ho_h, c_i, c_o, FQi, FQo, 480);
        attn_final_mfma<<<ns,64,0,stream>>>(FQi, FQo, O2);
        gemm_o3pool<<<ns/4,NTH,0,stream>>>(O2, fo_h, f_out_b, pooled, base);
    }

    // out = ELU(pooled @ lin_w^T + lin_b)  fp32, split-x3
    dim3 g6(256, 1);
    gemm_mfma_lin<<<g6,NTH,0,stream>>>(pooled, li_h, li_l, lin_b, (float*)d_out, 160);
}

// Round 10
// 1414.772 us; speedup vs baseline: 1.2452x; 1.2452x over previous
//
#include <hip/hip_runtime.h>
#include <hip/hip_bf16.h>
#include <math.h>

#define NTH 256

typedef __bf16 bf16x8 __attribute__((ext_vector_type(8)));
typedef float  f32x4  __attribute__((ext_vector_type(4)));
typedef unsigned short ushort;
typedef ushort u16x8 __attribute__((ext_vector_type(8)));

__device__ __forceinline__ ushort f2bf(float x){
    union { float f; unsigned int u; } v; v.f = x;
    unsigned int r = v.u + 0x7fffu + ((v.u >> 16) & 1u);
    return (ushort)(r >> 16);
}
__device__ __forceinline__ float bf2f(ushort h){
    union { unsigned int u; float f; } v; v.u = ((unsigned int)h) << 16;
    return v.f;
}

// ============================ prep kernels ============================
__global__ void prep_combined_bf(const float* __restrict__ Wq, const float* __restrict__ Wk,
                                 const float* __restrict__ Wv, const float* __restrict__ in_w,
                                 ushort* __restrict__ dh)
{
    int o = blockIdx.x*NTH + threadIdx.x;
    if (o >= 76800) return;
    int c = o/160, j = o - c*160;
    const float* Wsel = (c<160) ? Wq : (c<320) ? Wk : Wv;
    const float* wrow = Wsel + j*160;
    const float* irow = in_w + c*160;
    float s = 0.f;
    for (int k=0;k<160;k++) s = fmaf(wrow[k], irow[k], s);
    dh[o] = f2bf(s);
}

__global__ void prep_H_bf(const float* __restrict__ f_in_w, const float* __restrict__ out_w,
                          ushort* __restrict__ dh)
{
    int o = blockIdx.x*NTH + threadIdx.x;
    if (o >= 76800) return;
    int n = o/160, k = o - n*160;
    float s = 0.f;
    for (int c=0;c<160;c++) s = fmaf(f_in_w[n*160+c], out_w[c*160+k], s);
    dh[o] = f2bf(s);
}

__global__ void prep_cvec(const float* __restrict__ f_in_w, const float* __restrict__ out_b,
                          const float* __restrict__ f_in_b, float* __restrict__ cv)
{
    int n = blockIdx.x*NTH + threadIdx.x;
    if (n >= 480) return;
    float s = f_in_b[n];
    for (int c=0;c<160;c++) s = fmaf(f_in_w[n*160+c], out_b[c], s);
    cv[n] = s;
}

__global__ void prep_conv_bf1(const float* __restrict__ src, ushort* __restrict__ dh, int n)
{
    int o = blockIdx.x*NTH + threadIdx.x;
    if (o >= n) return;
    dh[o] = f2bf(src[o]);
}

__global__ void prep_conv_bf2(const float* __restrict__ src,
                              ushort* __restrict__ dh, ushort* __restrict__ dl, int n)
{
    int o = blockIdx.x*NTH + threadIdx.x;
    if (o >= n) return;
    float s = src[o];
    ushort h = f2bf(s);
    dh[o] = h; dl[o] = f2bf(s - bf2f(h));
}

// ============================ MFMA GEMM (fp32 A, split-x3) — final linear ============
__global__ __launch_bounds__(NTH)
void gemm_mfma_lin(const float* __restrict__ A,
                   const ushort* __restrict__ Wh, const ushort* __restrict__ Wl,
                   const float* __restrict__ bias, float* __restrict__ C, int N)
{
    __shared__ ushort sAh[128*40], sAl[128*40];
    __shared__ ushort sWh[160*40], sWl[160*40];

    const int tid = threadIdx.x;
    const int lane = tid & 63, wave = tid >> 6;
    const int wm = wave >> 1, wn = wave & 1;
    const int ln = lane & 15, g = lane >> 4;
    const long m0 = (long)blockIdx.x * 128;
    const int  n0 = blockIdx.y * 160;

    f32x4 acc[4][5];
#pragma unroll
    for (int mt=0;mt<4;mt++)
#pragma unroll
        for (int nt=0;nt<5;nt++)
#pragma unroll
            for (int r=0;r<4;r++) acc[mt][nt][r] = 0.f;

    for (int k0=0;k0<160;k0+=32){
#pragma unroll
        for (int i=0;i<4;i++){
            int f = tid + 256*i;
            int m = f >> 3, seg = f & 7;
            float4 v = *(const float4*)(A + (m0+m)*160 + k0 + seg*4);
            ushort4 hv, lv;
            hv.x = f2bf(v.x); lv.x = f2bf(v.x - bf2f(hv.x));
            hv.y = f2bf(v.y); lv.y = f2bf(v.y - bf2f(hv.y));
            hv.z = f2bf(v.z); lv.z = f2bf(v.z - bf2f(hv.z));
            hv.w = f2bf(v.w); lv.w = f2bf(v.w - bf2f(hv.w));
            *(ushort4*)(sAh + m*40 + seg*4) = hv;
            *(ushort4*)(sAl + m*40 + seg*4) = lv;
        }
#pragma unroll
        for (int i=0;i<5;i++){
            int e = tid + 256*i;
            int pl = (e >= 640);
            int idx = pl ? e-640 : e;
            int n = idx >> 2, seg = idx & 3;
            const ushort* src = (pl ? Wl : Wh) + (long)(n0+n)*160 + k0 + seg*8;
            ushort* dst = (pl ? sWl : sWh) + n*40 + seg*8;
            *(uint4*)dst = *(const uint4*)src;
        }
        __syncthreads();

        bf16x8 ah[4], al[4];
#pragma unroll
        for (int mt=0;mt<4;mt++){
            int off = (wm*64 + mt*16 + ln)*40 + g*8;
            ah[mt] = *(const bf16x8*)(sAh + off);
            al[mt] = *(const bf16x8*)(sAl + off);
        }
#pragma unroll
        for (int nt=0;nt<5;nt++){
            int offw = (wn*80 + nt*16 + ln)*40 + g*8;
            bf16x8 bh = *(const bf16x8*)(sWh + offw);
            bf16x8 bl = *(const bf16x8*)(sWl + offw);
#pragma unroll
            for (int mt=0;mt<4;mt++){
                acc[mt][nt] = __builtin_amdgcn_mfma_f32_16x16x32_bf16(ah[mt], bh, acc[mt][nt], 0,0,0);
                acc[mt][nt] = __builtin_amdgcn_mfma_f32_16x16x32_bf16(al[mt], bh, acc[mt][nt], 0,0,0);
                acc[mt][nt] = __builtin_amdgcn_mfma_f32_16x16x32_bf16(ah[mt], bl, acc[mt][nt], 0,0,0);
            }
        }
        __syncthreads();
    }

#pragma unroll
    for (int nt=0;nt<5;nt++){
        int col = n0 + wn*80 + nt*16 + ln;
        float bv = bias[col];
#pragma unroll
        for (int mt=0;mt<4;mt++){
#pragma unroll
            for (int r=0;r<4;r++){
                long row = m0 + wm*64 + mt*16 + g*4 + r;
                float x = acc[mt][nt][r] + bv;
                x = x > 0.f ? x : expm1f(x);
                C[row*N + col] = x;
            }
        }
    }
}

// ============================ bf16 GEMM (A bf16, W single-plane) ============
__global__ __launch_bounds__(NTH)
void gemm_bf(const ushort* __restrict__ A0, const ushort* __restrict__ A1,
             const ushort* __restrict__ Wh0, const ushort* __restrict__ Wh1,
             const float* __restrict__ b0, const float* __restrict__ b1,
             ushort* __restrict__ C0, ushort* __restrict__ C1, int N)
{
    const int z = blockIdx.z;
    const ushort* A  = z ? A1 : A0;
    const ushort* Wh = z ? Wh1 : Wh0;
    const float* bias = z ? b1 : b0;
    ushort* C = z ? C1 : C0;

    __shared__ ushort sA[128*40];
    __shared__ ushort sW[160*40];

    const int tid = threadIdx.x;
    const int lane = tid & 63, wave = tid >> 6;
    const int wm = wave >> 1, wn = wave & 1;
    const int ln = lane & 15, g = lane >> 4;
    const long m0 = (long)blockIdx.x * 128;
    const int  n0 = blockIdx.y * 160;

    f32x4 acc[4][5];
#pragma unroll
    for (int mt=0;mt<4;mt++)
#pragma unroll
        for (int nt=0;nt<5;nt++)
#pragma unroll
            for (int r=0;r<4;r++) acc[mt][nt][r] = 0.f;

    for (int k0=0;k0<160;k0+=32){
#pragma unroll
        for (int i=0;i<2;i++){
            int e = tid + 256*i;
            int m = e >> 2, seg = e & 3;
            *(uint4*)(sA + m*40 + seg*8) =
                *(const uint4*)(A + (m0+m)*160 + k0 + seg*8);
        }
#pragma unroll
        for (int i=0;i<3;i++){
            int e = tid + 256*i;
            if (e < 640){
                int n = e >> 2, seg = e & 3;
                *(uint4*)(sW + n*40 + seg*8) =
                    *(const uint4*)(Wh + (long)(n0+n)*160 + k0 + seg*8);
            }
        }
        __syncthreads();

        bf16x8 af[4];
#pragma unroll
        for (int mt=0;mt<4;mt++)
            af[mt] = *(const bf16x8*)(sA + (wm*64 + mt*16 + ln)*40 + g*8);
#pragma unroll
        for (int nt=0;nt<5;nt++){
            bf16x8 bh = *(const bf16x8*)(sW + (wn*80 + nt*16 + ln)*40 + g*8);
#pragma unroll
            for (int mt=0;mt<4;mt++)
                acc[mt][nt] = __builtin_amdgcn_mfma_f32_16x16x32_bf16(af[mt], bh, acc[mt][nt], 0,0,0);
        }
        __syncthreads();
    }

#pragma unroll
    for (int nt=0;nt<5;nt++){
        int col = n0 + wn*80 + nt*16 + ln;
        float bv = bias[col];
#pragma unroll
        for (int mt=0;mt<4;mt++){
#pragma unroll
            for (int r=0;r<4;r++){
                long row = m0 + wm*64 + mt*16 + g*4 + r;
                C[row*N + col] = f2bf(acc[mt][nt][r] + bv);
            }
        }
    }
}

// ============================ MFMA attention, layers 1/2 (round-8 proven) ============
__global__ __launch_bounds__(64)
void attn_layer_mfma(const ushort* __restrict__ XPi, const ushort* __restrict__ XPo,
                     const int* __restrict__ in_idx, const int* __restrict__ out_idx,
                     ushort* __restrict__ Oi, ushort* __restrict__ Oo, int node_base)
{
    const ushort* XP = blockIdx.y ? XPo : XPi;
    const int*  idx  = blockIdx.y ? out_idx : in_idx;
    ushort* O        = blockIdx.y ? Oo : Oi;

    __shared__ ushort XPg[16*496];
    __shared__ ushort Pall[5*16*24];

    const int lane = threadIdx.x;
    const int ln = lane & 15, q = lane >> 4;
    const int node = node_base + blockIdx.x;
    const int bb = node >> 12, nn = node & 4095;

    int idxv = nn;
    if (lane >= 1 && lane < 16) idxv = idx[(long)node*15 + lane-1];

#pragma unroll
    for (int i=0;i<15;i++){
        int e = lane + 64*i;
        int r = e/60, c = e - r*60;
        int rowg = __shfl(idxv, r);
        *(uint4*)(XPg + r*496 + c*8) =
            *(const uint4*)(XP + (long)(bb*4096 + rowg)*480 + c*8);
    }
    __syncthreads();

    const float scale = 0.17677669529663687f;
#pragma unroll
    for (int h=0;h<5;h++){
        bf16x8 ka = *(const bf16x8*)(XPg + ln*496 + 160 + h*32 + q*8);
        bf16x8 qb = *(const bf16x8*)(XPg + ln*496 +       h*32 + q*8);
        f32x4 s = {0.f,0.f,0.f,0.f};
        s = __builtin_amdgcn_mfma_f32_16x16x32_bf16(ka, qb, s, 0,0,0);
        float x[4], m = -1e30f;
#pragma unroll
        for (int r=0;r<4;r++){ x[r] = s[r]*scale; m = fmaxf(m, x[r]); }
        m = fmaxf(m, __shfl_xor(m, 16));
        m = fmaxf(m, __shfl_xor(m, 32));
        float e0[4], sum = 0.f;
#pragma unroll
        for (int r=0;r<4;r++){ e0[r] = __expf(x[r]-m); sum += e0[r]; }
        sum += __shfl_xor(sum, 16);
        sum += __shfl_xor(sum, 32);
        float inv = 1.f/sum;
        ushort4 pw;
        pw.x = f2bf(e0[0]*inv); pw.y = f2bf(e0[1]*inv);
        pw.z = f2bf(e0[2]*inv); pw.w = f2bf(e0[3]*inv);
        *(ushort4*)(Pall + h*384 + ln*24 + q*4) = pw;
    }
    __syncthreads();

#pragma unroll
    for (int h=0;h<5;h++){
        u16x8 ta;
#pragma unroll
        for (int jj=0;jj<8;jj++) ta[jj] = 0;
        if (q < 2) ta = *(const u16x8*)(Pall + h*384 + ln*24 + q*8);
        bf16x8 ap = *(bf16x8*)&ta;
#pragma unroll
        for (int half=0; half<2; half++){
            u16x8 tb;
#pragma unroll
            for (int jj=0;jj<8;jj++) tb[jj] = 0;
            if (q < 2){
#pragma unroll
                for (int jj=0;jj<8;jj++)
                    tb[jj] = XPg[(q*8+jj)*496 + 320 + h*32 + half*16 + ln];
            }
            bf16x8 bv = *(bf16x8*)&tb;
            f32x4 o = {0.f,0.f,0.f,0.f};
            o = __builtin_amdgcn_mfma_f32_16x16x32_bf16(ap, bv, o, 0,0,0);
#pragma unroll
            for (int r=0;r<4;r++)
                O[(long)(blockIdx.x*16 + q*4 + r)*160 + h*32 + half*16 + ln] = f2bf(o[r]);
        }
    }
}

// ============================ MFMA final attention (round-8 proven) ============
__global__ __launch_bounds__(64)
void attn_final_mfma(const ushort* __restrict__ FQi, const ushort* __restrict__ FQo,
                     ushort* __restrict__ O2)
{
    __shared__ ushort F[32*328];
    __shared__ ushort P[32*40];

    const int lane = threadIdx.x;
    const int ln = lane & 15, q = lane >> 4;
    const int nl = blockIdx.x;

#pragma unroll
    for (int i=0;i<20;i++){
        int e = lane + 64*i;
        int r = e/40, c = e - r*40;
        const ushort* src = (r<16) ? (FQi + (long)(nl*16+r)*480 + c*8)
                                   : (FQo + (long)(nl*16+r-16)*480 + c*8);
        *(uint4*)(F + r*328 + c*8) = *(const uint4*)src;
    }
    __syncthreads();

    f32x4 sc[2][2];
#pragma unroll
    for (int ti=0;ti<2;ti++)
#pragma unroll
        for (int tj=0;tj<2;tj++){
            f32x4 a = {0.f,0.f,0.f,0.f};
#pragma unroll
            for (int kc=0;kc<5;kc++){
                bf16x8 ka = *(const bf16x8*)(F + (tj*16+ln)*328 + 160 + kc*32 + q*8);
                bf16x8 qb = *(const bf16x8*)(F + (ti*16+ln)*328 +       kc*32 + q*8);
                a = __builtin_amdgcn_mfma_f32_16x16x32_bf16(ka, qb, a, 0,0,0);
            }
            sc[ti][tj] = a;
        }

    const float scale = 0.07905694150420949f;
#pragma unroll
    for (int ti=0;ti<2;ti++){
        float x[2][4], m = -1e30f;
#pragma unroll
        for (int tj=0;tj<2;tj++)
#pragma unroll
            for (int r=0;r<4;r++){ x[tj][r] = sc[ti][tj][r]*scale; m = fmaxf(m, x[tj][r]); }
        m = fmaxf(m, __shfl_xor(m, 16));
        m = fmaxf(m, __shfl_xor(m, 32));
        float sum = 0.f;
#pragma unroll
        for (int tj=0;tj<2;tj++)
#pragma unroll
            for (int r=0;r<4;r++){ x[tj][r] = __expf(x[tj][r]-m); sum += x[tj][r]; }
        sum += __shfl_xor(sum, 16);
        sum += __shfl_xor(sum, 32);
        float inv = 1.f/sum;
#pragma unroll
        for (int tj=0;tj<2;tj++){
            ushort4 pw;
            pw.x = f2bf(x[tj][0]*inv); pw.y = f2bf(x[tj][1]*inv);
            pw.z = f2bf(x[tj][2]*inv); pw.w = f2bf(x[tj][3]*inv);
            *(ushort4*)(P + (ti*16+ln)*40 + tj*16 + q*4) = pw;
        }
    }
    __syncthreads();

#pragma unroll
    for (int i=0;i<10;i++){
        int e = lane + 64*i;
        int r = e/20, c = e - r*20;
        const ushort* src = (r<16) ? (FQi + (long)(nl*16+r)*480 + 320 + c*8)
                                   : (FQo + (long)(nl*16+r-16)*480 + 320 + c*8);
        *(uint4*)(F + r*168 + c*8) = *(const uint4*)src;
    }
    __syncthreads();

    bf16x8 ap[2];
#pragma unroll
    for (int mi=0;mi<2;mi++)
        ap[mi] = *(const bf16x8*)(P + (mi*16+ln)*40 + q*8);
#pragma unroll
    for (int nt=0;nt<10;nt++){
        u16x8 tb;
#pragma unroll
        for (int jj=0;jj<8;jj++) tb[jj] = F[(q*8+jj)*168 + nt*16 + ln];
        bf16x8 bv = *(bf16x8*)&tb;
#pragma unroll
        for (int mi=0;mi<2;mi++){
            f32x4 o = {0.f,0.f,0.f,0.f};
            o = __builtin_amdgcn_mfma_f32_16x16x32_bf16(ap[mi], bv, o, 0,0,0);
#pragma unroll
            for (int r=0;r<4;r++)
                O2[(long)(nl*32 + mi*16 + q*4 + r)*160 + nt*16 + ln] = f2bf(o[r]);
        }
    }
}

// ============================ O3 GEMM + fused max-pool (round-8 proven) ============
__global__ __launch_bounds__(512)
void gemm_o3pool(const ushort* __restrict__ A,
                 const ushort* __restrict__ Wh,
                 const float* __restrict__ fb, float* __restrict__ pooled,
                 int node_base)
{
    __shared__ ushort sA[128*168];
    __shared__ ushort sW[160*40];

    const int tid = threadIdx.x;
    const int lane = tid & 63, wave = tid >> 6;
    const int wm = wave >> 1, wn = wave & 1;
    const int ln = lane & 15, q = lane >> 4;
    const long m0 = (long)blockIdx.x * 128;

#pragma unroll
    for (int i=0;i<5;i++){
        int e = tid + 512*i;
        int m = e/20, s = e - m*20;
        *(uint4*)(sA + m*168 + s*8) = *(const uint4*)(A + (m0+m)*160 + s*8);
    }

    f32x4 acc[2][5];
#pragma unroll
    for (int mt=0;mt<2;mt++)
#pragma unroll
        for (int nt=0;nt<5;nt++)
#pragma unroll
            for (int r=0;r<4;r++) acc[mt][nt][r] = 0.f;

    for (int kc=0;kc<5;kc++){
        const int k0 = kc*32;
        __syncthreads();
#pragma unroll
        for (int i=0;i<2;i++){
            int e = tid + 512*i;
            if (e < 640){
                int n = e >> 2, s = e & 3;
                *(uint4*)(sW + n*40 + s*8) =
                    *(const uint4*)(Wh + n*160 + k0 + s*8);
            }
        }
        __syncthreads();

        bf16x8 af[2];
#pragma unroll
        for (int mt=0;mt<2;mt++)
            af[mt] = *(const bf16x8*)(sA + (wm*32 + mt*16 + ln)*168 + k0 + q*8);
#pragma unroll
        for (int nt=0;nt<5;nt++){
            bf16x8 bh = *(const bf16x8*)(sW + (wn*80 + nt*16 + ln)*40 + q*8);
#pragma unroll
            for (int mt=0;mt<2;mt++)
                acc[mt][nt] = __builtin_amdgcn_mfma_f32_16x16x32_bf16(af[mt], bh, acc[mt][nt], 0,0,0);
        }
    }

    const int node = node_base + blockIdx.x*4 + wm;
#pragma unroll
    for (int nt=0;nt<5;nt++){
        float m = acc[0][nt][0];
#pragma unroll
        for (int mt=0;mt<2;mt++)
#pragma unroll
            for (int r=0;r<4;r++) m = fmaxf(m, acc[mt][nt][r]);
        m = fmaxf(m, __shfl_xor(m, 16));
        m = fmaxf(m, __shfl_xor(m, 32));
        if (q == 0){
            int col = wn*80 + nt*16 + ln;
            pooled[(long)node*160 + col] = m + fb[col];
        }
    }
}

// ============================ host ============================
extern "C" void kernel_launch(void* const* d_in, const int* in_sizes, int n_in,
                              void* d_out, int out_size, void* d_ws, size_t ws_size,
                              hipStream_t stream)
{
    const float* X       = (const float*)d_in[0];
    const int*   in_idx  = (const int*)  d_in[1];
    const int*   out_idx = (const int*)  d_in[2];
    const float* iWq     = (const float*)d_in[3];
    const float* iWk     = (const float*)d_in[4];
    const float* iWv     = (const float*)d_in[5];
    const float* i_in_w  = (const float*)d_in[6];
    const float* i_in_b  = (const float*)d_in[7];
    const float* i_out_w = (const float*)d_in[8];
    const float* i_out_b = (const float*)d_in[9];
    const float* oWq     = (const float*)d_in[10];
    const float* oWk     = (const float*)d_in[11];
    const float* oWv     = (const float*)d_in[12];
    const float* o_in_w  = (const float*)d_in[13];
    const float* o_in_b  = (const float*)d_in[14];
    const float* o_out_w = (const float*)d_in[15];
    const float* o_out_b = (const float*)d_in[16];
    const float* f_in_w  = (const float*)d_in[17];
    const float* f_in_b  = (const float*)d_in[18];
    const float* f_out_w = (const float*)d_in[19];
    const float* f_out_b = (const float*)d_in[20];
    const float* lin_w   = (const float*)d_in[21];
    const float* lin_b   = (const float*)d_in[22];

    float* ws = (float*)d_ws;
    float* pooled = ws;                           // 32768*160 fp32
    float* c_i    = pooled + 5242880;             // 480
    float* c_o    = c_i + 480;
    ushort* ub    = (ushort*)(c_o + 480);
    ushort* Xb    = ub;                           // 32768*160 bf16
    ushort* XPb_i = Xb + 5242880;                 // 32768*480 bf16
    ushort* XPb_o = XPb_i + 15728640;
    ushort* Wci_h = XPb_o + 15728640;             // 76800 each
    ushort* Wco_h = Wci_h + 76800;
    ushort* Hi_h  = Wco_h + 76800;
    ushort* Ho_h  = Hi_h  + 76800;
    ushort* fo_h  = Ho_h  + 76800;                // 25600 each
    ushort* li_h  = fo_h  + 25600;
    ushort* li_l  = li_h  + 25600;
    ushort* sb_us = li_l + 25600;
    const unsigned long long fixed = 23785920ULL;   // floats

    size_t avail = ws_size / 4;
    int ns = 4096;
    while (ns > 64 && fixed + 12800ULL*ns > avail) ns >>= 1;

    ushort* O_i = sb_us;                          // ns*16*160
    ushort* O_o = O_i + (size_t)2560*ns;
    ushort* FQi = O_o + (size_t)2560*ns;          // ns*16*480
    ushort* FQo = FQi + (size_t)7680*ns;
    ushort* O2  = FQo + (size_t)7680*ns;          // ns*32*160

    prep_combined_bf<<<300,NTH,0,stream>>>(iWq,iWk,iWv,i_in_w, Wci_h);
    prep_combined_bf<<<300,NTH,0,stream>>>(oWq,oWk,oWv,o_in_w, Wco_h);
    prep_H_bf<<<300,NTH,0,stream>>>(f_in_w, i_out_w, Hi_h);
    prep_H_bf<<<300,NTH,0,stream>>>(f_in_w, o_out_w, Ho_h);
    prep_cvec<<<2,NTH,0,stream>>>(f_in_w, i_out_b, f_in_b, c_i);
    prep_cvec<<<2,NTH,0,stream>>>(f_in_w, o_out_b, f_in_b, c_o);
    prep_conv_bf1<<<100,NTH,0,stream>>>(f_out_w, fo_h, 25600);
    prep_conv_bf2<<<100,NTH,0,stream>>>(lin_w,   li_h, li_l, 25600);
    prep_conv_bf1<<<20480,NTH,0,stream>>>(X, Xb, 5242880);

    // XP = Xb @ Wc^T + in_b  -> bf16 (both layers via z)
    dim3 g1(256, 3, 2);
    gemm_bf<<<g1,NTH,0,stream>>>(Xb, Xb, Wci_h, Wco_h, i_in_b, o_in_b,
                                 XPb_i, XPb_o, 480);

    int S = 32768 / ns;
    for (int s=0;s<S;s++){
        int base = s*ns;
        dim3 ga(ns, 2);
        attn_layer_mfma<<<ga,64,0,stream>>>(XPb_i, XPb_o, in_idx, out_idx, O_i, O_o, base);
        dim3 g3(ns/8, 3, 2);
        gemm_bf<<<g3,NTH,0,stream>>>(O_i, O_o, Hi_h, Ho_h, c_i, c_o, FQi, FQo, 480);
        attn_final_mfma<<<ns,64,0,stream>>>(FQi, FQo, O2);
        gemm_o3pool<<<ns/4,512,0,stream>>>(O2, fo_h, f_out_b, pooled, base);
    }

    // out = ELU(pooled @ lin_w^T + lin_b)  fp32, split-x3
    dim3 g6(256, 1);
    gemm_mfma_lin<<<g6,NTH,0,stream>>>(pooled, li_h, li_l, lin_b, (float*)d_out, 160);
}

// Round 11
// 1157.652 us; speedup vs baseline: 1.5218x; 1.2221x over previous
//
#include <hip/hip_runtime.h>
#include <hip/hip_bf16.h>
#include <math.h>

#define NTH 256

typedef __bf16 bf16x8 __attribute__((ext_vector_type(8)));
typedef float  f32x4  __attribute__((ext_vector_type(4)));
typedef unsigned short ushort;
typedef ushort u16x8 __attribute__((ext_vector_type(8)));

__device__ __forceinline__ ushort f2bf(float x){
    union { float f; unsigned int u; } v; v.f = x;
    unsigned int r = v.u + 0x7fffu + ((v.u >> 16) & 1u);
    return (ushort)(r >> 16);
}
__device__ __forceinline__ float bf2f(ushort h){
    union { unsigned int u; float f; } v; v.u = ((unsigned int)h) << 16;
    return v.f;
}

// ============================ prep kernels ============================
__global__ void prep_combined_bf(const float* __restrict__ Wq, const float* __restrict__ Wk,
                                 const float* __restrict__ Wv, const float* __restrict__ in_w,
                                 ushort* __restrict__ dh)
{
    int o = blockIdx.x*NTH + threadIdx.x;
    if (o >= 76800) return;
    int c = o/160, j = o - c*160;
    const float* Wsel = (c<160) ? Wq : (c<320) ? Wk : Wv;
    const float* wrow = Wsel + j*160;
    const float* irow = in_w + c*160;
    float s = 0.f;
    for (int k=0;k<160;k++) s = fmaf(wrow[k], irow[k], s);
    dh[o] = f2bf(s);
}

// H rows 0..319 -> bf16 dh; rows 320..479 -> fp32 tmp (for fo-fold)
__global__ void prep_H_split(const float* __restrict__ f_in_w, const float* __restrict__ out_w,
                             ushort* __restrict__ dh, float* __restrict__ tmp)
{
    int o = blockIdx.x*NTH + threadIdx.x;
    if (o >= 76800) return;
    int n = o/160, k = o - n*160;
    float s = 0.f;
    for (int c=0;c<160;c++) s = fmaf(f_in_w[n*160+c], out_w[c*160+k], s);
    if (n < 320) dh[o] = f2bf(s);
    else         tmp[(n-320)*160 + k] = s;
}

// H'[320+n][k] = sum_j f_out_w[n][j] * Hv[j][k]  (fold fo into fv projection)
__global__ void prep_H_fold(const float* __restrict__ fo, const float* __restrict__ Hv,
                            ushort* __restrict__ dh)
{
    int o = blockIdx.x*NTH + threadIdx.x;
    if (o >= 25600) return;
    int n = o/160, k = o - n*160;
    float s = 0.f;
    for (int j=0;j<160;j++) s = fmaf(fo[n*160+j], Hv[j*160+k], s);
    dh[(320+n)*160 + k] = f2bf(s);
}

// cvt[n] = f_in_w[n].out_b + f_in_b[n]  (full 480, fp32)
__global__ void prep_cvec(const float* __restrict__ f_in_w, const float* __restrict__ out_b,
                          const float* __restrict__ f_in_b, float* __restrict__ cvt)
{
    int n = blockIdx.x*NTH + threadIdx.x;
    if (n >= 480) return;
    float s = f_in_b[n];
    for (int c=0;c<160;c++) s = fmaf(f_in_w[n*160+c], out_b[c], s);
    cvt[n] = s;
}

// cv[0..319]=cvt; cv[320+n] = sum_j fo[n][j]*cvt[320+j]
__global__ void prep_cvec_fold(const float* __restrict__ fo, const float* __restrict__ cvt,
                               float* __restrict__ cv)
{
    int n = blockIdx.x*NTH + threadIdx.x;
    if (n >= 480) return;
    if (n < 320){ cv[n] = cvt[n]; return; }
    int m = n - 320;
    float s = 0.f;
    for (int j=0;j<160;j++) s = fmaf(fo[m*160+j], cvt[320+j], s);
    cv[n] = s;
}

__global__ void prep_conv_bf1(const float* __restrict__ src, ushort* __restrict__ dh, int n)
{
    int o = blockIdx.x*NTH + threadIdx.x;
    if (o >= n) return;
    dh[o] = f2bf(src[o]);
}

__global__ void prep_conv_bf2(const float* __restrict__ src,
                              ushort* __restrict__ dh, ushort* __restrict__ dl, int n)
{
    int o = blockIdx.x*NTH + threadIdx.x;
    if (o >= n) return;
    float s = src[o];
    ushort h = f2bf(s);
    dh[o] = h; dl[o] = f2bf(s - bf2f(h));
}

// ============================ MFMA GEMM (fp32 A, split-x3) — final linear ============
__global__ __launch_bounds__(NTH)
void gemm_mfma_lin(const float* __restrict__ A,
                   const ushort* __restrict__ Wh, const ushort* __restrict__ Wl,
                   const float* __restrict__ bias, float* __restrict__ C, int N)
{
    __shared__ ushort sAh[128*40], sAl[128*40];
    __shared__ ushort sWh[160*40], sWl[160*40];

    const int tid = threadIdx.x;
    const int lane = tid & 63, wave = tid >> 6;
    const int wm = wave >> 1, wn = wave & 1;
    const int ln = lane & 15, g = lane >> 4;
    const long m0 = (long)blockIdx.x * 128;
    const int  n0 = blockIdx.y * 160;

    f32x4 acc[4][5];
#pragma unroll
    for (int mt=0;mt<4;mt++)
#pragma unroll
        for (int nt=0;nt<5;nt++)
#pragma unroll
            for (int r=0;r<4;r++) acc[mt][nt][r] = 0.f;

    for (int k0=0;k0<160;k0+=32){
#pragma unroll
        for (int i=0;i<4;i++){
            int f = tid + 256*i;
            int m = f >> 3, seg = f & 7;
            float4 v = *(const float4*)(A + (m0+m)*160 + k0 + seg*4);
            ushort4 hv, lv;
            hv.x = f2bf(v.x); lv.x = f2bf(v.x - bf2f(hv.x));
            hv.y = f2bf(v.y); lv.y = f2bf(v.y - bf2f(hv.y));
            hv.z = f2bf(v.z); lv.z = f2bf(v.z - bf2f(hv.z));
            hv.w = f2bf(v.w); lv.w = f2bf(v.w - bf2f(hv.w));
            *(ushort4*)(sAh + m*40 + seg*4) = hv;
            *(ushort4*)(sAl + m*40 + seg*4) = lv;
        }
#pragma unroll
        for (int i=0;i<5;i++){
            int e = tid + 256*i;
            int pl = (e >= 640);
            int idx = pl ? e-640 : e;
            int n = idx >> 2, seg = idx & 3;
            const ushort* src = (pl ? Wl : Wh) + (long)(n0+n)*160 + k0 + seg*8;
            ushort* dst = (pl ? sWl : sWh) + n*40 + seg*8;
            *(uint4*)dst = *(const uint4*)src;
        }
        __syncthreads();

        bf16x8 ah[4], al[4];
#pragma unroll
        for (int mt=0;mt<4;mt++){
            int off = (wm*64 + mt*16 + ln)*40 + g*8;
            ah[mt] = *(const bf16x8*)(sAh + off);
            al[mt] = *(const bf16x8*)(sAl + off);
        }
#pragma unroll
        for (int nt=0;nt<5;nt++){
            int offw = (wn*80 + nt*16 + ln)*40 + g*8;
            bf16x8 bh = *(const bf16x8*)(sWh + offw);
            bf16x8 bl = *(const bf16x8*)(sWl + offw);
#pragma unroll
            for (int mt=0;mt<4;mt++){
                acc[mt][nt] = __builtin_amdgcn_mfma_f32_16x16x32_bf16(ah[mt], bh, acc[mt][nt], 0,0,0);
                acc[mt][nt] = __builtin_amdgcn_mfma_f32_16x16x32_bf16(al[mt], bh, acc[mt][nt], 0,0,0);
                acc[mt][nt] = __builtin_amdgcn_mfma_f32_16x16x32_bf16(ah[mt], bl, acc[mt][nt], 0,0,0);
            }
        }
        __syncthreads();
    }

#pragma unroll
    for (int nt=0;nt<5;nt++){
        int col = n0 + wn*80 + nt*16 + ln;
        float bv = bias[col];
#pragma unroll
        for (int mt=0;mt<4;mt++){
#pragma unroll
            for (int r=0;r<4;r++){
                long row = m0 + wm*64 + mt*16 + g*4 + r;
                float x = acc[mt][nt][r] + bv;
                x = x > 0.f ? x : expm1f(x);
                C[row*N + col] = x;
            }
        }
    }
}

// ============================ bf16 GEMM (A bf16, W single-plane) ============
__global__ __launch_bounds__(NTH)
void gemm_bf(const ushort* __restrict__ A0, const ushort* __restrict__ A1,
             const ushort* __restrict__ Wh0, const ushort* __restrict__ Wh1,
             const float* __restrict__ b0, const float* __restrict__ b1,
             ushort* __restrict__ C0, ushort* __restrict__ C1, int N)
{
    const int z = blockIdx.z;
    const ushort* A  = z ? A1 : A0;
    const ushort* Wh = z ? Wh1 : Wh0;
    const float* bias = z ? b1 : b0;
    ushort* C = z ? C1 : C0;

    __shared__ ushort sA[128*40];
    __shared__ ushort sW[160*40];

    const int tid = threadIdx.x;
    const int lane = tid & 63, wave = tid >> 6;
    const int wm = wave >> 1, wn = wave & 1;
    const int ln = lane & 15, g = lane >> 4;
    const long m0 = (long)blockIdx.x * 128;
    const int  n0 = blockIdx.y * 160;

    f32x4 acc[4][5];
#pragma unroll
    for (int mt=0;mt<4;mt++)
#pragma unroll
        for (int nt=0;nt<5;nt++)
#pragma unroll
            for (int r=0;r<4;r++) acc[mt][nt][r] = 0.f;

    for (int k0=0;k0<160;k0+=32){
#pragma unroll
        for (int i=0;i<2;i++){
            int e = tid + 256*i;
            int m = e >> 2, seg = e & 3;
            *(uint4*)(sA + m*40 + seg*8) =
                *(const uint4*)(A + (m0+m)*160 + k0 + seg*8);
        }
#pragma unroll
        for (int i=0;i<3;i++){
            int e = tid + 256*i;
            if (e < 640){
                int n = e >> 2, seg = e & 3;
                *(uint4*)(sW + n*40 + seg*8) =
                    *(const uint4*)(Wh + (long)(n0+n)*160 + k0 + seg*8);
            }
        }
        __syncthreads();

        bf16x8 af[4];
#pragma unroll
        for (int mt=0;mt<4;mt++)
            af[mt] = *(const bf16x8*)(sA + (wm*64 + mt*16 + ln)*40 + g*8);
#pragma unroll
        for (int nt=0;nt<5;nt++){
            bf16x8 bh = *(const bf16x8*)(sW + (wn*80 + nt*16 + ln)*40 + g*8);
#pragma unroll
            for (int mt=0;mt<4;mt++)
                acc[mt][nt] = __builtin_amdgcn_mfma_f32_16x16x32_bf16(af[mt], bh, acc[mt][nt], 0,0,0);
        }
        __syncthreads();
    }

#pragma unroll
    for (int nt=0;nt<5;nt++){
        int col = n0 + wn*80 + nt*16 + ln;
        float bv = bias[col];
#pragma unroll
        for (int mt=0;mt<4;mt++){
#pragma unroll
            for (int r=0;r<4;r++){
                long row = m0 + wm*64 + mt*16 + g*4 + r;
                C[row*N + col] = f2bf(acc[mt][nt][r] + bv);
            }
        }
    }
}

// ============================ MFMA attention, layers 1/2 ============
__global__ __launch_bounds__(64)
void attn_layer_mfma(const ushort* __restrict__ XPi, const ushort* __restrict__ XPo,
                     const int* __restrict__ in_idx, const int* __restrict__ out_idx,
                     ushort* __restrict__ Oi, ushort* __restrict__ Oo, int node_base)
{
    const ushort* XP = blockIdx.y ? XPo : XPi;
    const int*  idx  = blockIdx.y ? out_idx : in_idx;
    ushort* O        = blockIdx.y ? Oo : Oi;

    __shared__ ushort XPg[16*496];
    __shared__ ushort Pall[5*16*24];

    const int lane = threadIdx.x;
    const int ln = lane & 15, q = lane >> 4;
    const int node = node_base + blockIdx.x;
    const int bb = node >> 12, nn = node & 4095;

    int idxv = nn;
    if (lane >= 1 && lane < 16) idxv = idx[(long)node*15 + lane-1];

#pragma unroll
    for (int i=0;i<15;i++){
        int e = lane + 64*i;
        int r = e/60, c = e - r*60;
        int rowg = __shfl(idxv, r);
        *(uint4*)(XPg + r*496 + c*8) =
            *(const uint4*)(XP + (long)(bb*4096 + rowg)*480 + c*8);
    }
    __syncthreads();

    const float scale = 0.17677669529663687f;
#pragma unroll
    for (int h=0;h<5;h++){
        bf16x8 ka = *(const bf16x8*)(XPg + ln*496 + 160 + h*32 + q*8);
        bf16x8 qb = *(const bf16x8*)(XPg + ln*496 +       h*32 + q*8);
        f32x4 s = {0.f,0.f,0.f,0.f};
        s = __builtin_amdgcn_mfma_f32_16x16x32_bf16(ka, qb, s, 0,0,0);
        float x[4], m = -1e30f;
#pragma unroll
        for (int r=0;r<4;r++){ x[r] = s[r]*scale; m = fmaxf(m, x[r]); }
        m = fmaxf(m, __shfl_xor(m, 16));
        m = fmaxf(m, __shfl_xor(m, 32));
        float e0[4], sum = 0.f;
#pragma unroll
        for (int r=0;r<4;r++){ e0[r] = __expf(x[r]-m); sum += e0[r]; }
        sum += __shfl_xor(sum, 16);
        sum += __shfl_xor(sum, 32);
        float inv = 1.f/sum;
        ushort4 pw;
        pw.x = f2bf(e0[0]*inv); pw.y = f2bf(e0[1]*inv);
        pw.z = f2bf(e0[2]*inv); pw.w = f2bf(e0[3]*inv);
        *(ushort4*)(Pall + h*384 + ln*24 + q*4) = pw;
    }
    __syncthreads();

#pragma unroll
    for (int h=0;h<5;h++){
        u16x8 ta;
#pragma unroll
        for (int jj=0;jj<8;jj++) ta[jj] = 0;
        if (q < 2) ta = *(const u16x8*)(Pall + h*384 + ln*24 + q*8);
        bf16x8 ap = *(bf16x8*)&ta;
#pragma unroll
        for (int half=0; half<2; half++){
            u16x8 tb;
#pragma unroll
            for (int jj=0;jj<8;jj++) tb[jj] = 0;
            if (q < 2){
#pragma unroll
                for (int jj=0;jj<8;jj++)
                    tb[jj] = XPg[(q*8+jj)*496 + 320 + h*32 + half*16 + ln];
            }
            bf16x8 bv = *(bf16x8*)&tb;
            f32x4 o = {0.f,0.f,0.f,0.f};
            o = __builtin_amdgcn_mfma_f32_16x16x32_bf16(ap, bv, o, 0,0,0);
#pragma unroll
            for (int r=0;r<4;r++)
                O[(long)(blockIdx.x*16 + q*4 + r)*160 + h*32 + half*16 + ln] = f2bf(o[r]);
        }
    }
}

// ============================ MFMA final attention + fused max-pool ============
// fv slot of FQ already holds fv' = fv @ fo^T (fold in prep), so PV output IS f.
// Epilogue pools col-max over the node's 32 rows and writes pooled fp32.
__global__ __launch_bounds__(64)
void attn_final_pool(const ushort* __restrict__ FQi, const ushort* __restrict__ FQo,
                     const float* __restrict__ fb, float* __restrict__ pooled,
                     int node_base)
{
    __shared__ ushort F[32*328];
    __shared__ ushort P[32*40];

    const int lane = threadIdx.x;
    const int ln = lane & 15, q = lane >> 4;
    const int nl = blockIdx.x;

#pragma unroll
    for (int i=0;i<20;i++){
        int e = lane + 64*i;
        int r = e/40, c = e - r*40;
        const ushort* src = (r<16) ? (FQi + (long)(nl*16+r)*480 + c*8)
                                   : (FQo + (long)(nl*16+r-16)*480 + c*8);
        *(uint4*)(F + r*328 + c*8) = *(const uint4*)src;
    }
    __syncthreads();

    f32x4 sc[2][2];
#pragma unroll
    for (int ti=0;ti<2;ti++)
#pragma unroll
        for (int tj=0;tj<2;tj++){
            f32x4 a = {0.f,0.f,0.f,0.f};
#pragma unroll
            for (int kc=0;kc<5;kc++){
                bf16x8 ka = *(const bf16x8*)(F + (tj*16+ln)*328 + 160 + kc*32 + q*8);
                bf16x8 qb = *(const bf16x8*)(F + (ti*16+ln)*328 +       kc*32 + q*8);
                a = __builtin_amdgcn_mfma_f32_16x16x32_bf16(ka, qb, a, 0,0,0);
            }
            sc[ti][tj] = a;
        }

    const float scale = 0.07905694150420949f;
#pragma unroll
    for (int ti=0;ti<2;ti++){
        float x[2][4], m = -1e30f;
#pragma unroll
        for (int tj=0;tj<2;tj++)
#pragma unroll
            for (int r=0;r<4;r++){ x[tj][r] = sc[ti][tj][r]*scale; m = fmaxf(m, x[tj][r]); }
        m = fmaxf(m, __shfl_xor(m, 16));
        m = fmaxf(m, __shfl_xor(m, 32));
        float sum = 0.f;
#pragma unroll
        for (int tj=0;tj<2;tj++)
#pragma unroll
            for (int r=0;r<4;r++){ x[tj][r] = __expf(x[tj][r]-m); sum += x[tj][r]; }
        sum += __shfl_xor(sum, 16);
        sum += __shfl_xor(sum, 32);
        float inv = 1.f/sum;
#pragma unroll
        for (int tj=0;tj<2;tj++){
            ushort4 pw;
            pw.x = f2bf(x[tj][0]*inv); pw.y = f2bf(x[tj][1]*inv);
            pw.z = f2bf(x[tj][2]*inv); pw.w = f2bf(x[tj][3]*inv);
            *(ushort4*)(P + (ti*16+ln)*40 + tj*16 + q*4) = pw;
        }
    }
    __syncthreads();

    // stage fv' (cols 320..479) into F at stride 168
#pragma unroll
    for (int i=0;i<10;i++){
        int e = lane + 64*i;
        int r = e/20, c = e - r*20;
        const ushort* src = (r<16) ? (FQi + (long)(nl*16+r)*480 + 320 + c*8)
                                   : (FQo + (long)(nl*16+r-16)*480 + 320 + c*8);
        *(uint4*)(F + r*168 + c*8) = *(const uint4*)src;
    }
    __syncthreads();

    bf16x8 ap[2];
#pragma unroll
    for (int mi=0;mi<2;mi++)
        ap[mi] = *(const bf16x8*)(P + (mi*16+ln)*40 + q*8);

    const int node = node_base + nl;
#pragma unroll
    for (int nt=0;nt<10;nt++){
        u16x8 tb;
#pragma unroll
        for (int jj=0;jj<8;jj++) tb[jj] = F[(q*8+jj)*168 + nt*16 + ln];
        bf16x8 bv = *(bf16x8*)&tb;
        float vmax = -1e30f;
#pragma unroll
        for (int mi=0;mi<2;mi++){
            f32x4 o = {0.f,0.f,0.f,0.f};
            o = __builtin_amdgcn_mfma_f32_16x16x32_bf16(ap[mi], bv, o, 0,0,0);
#pragma unroll
            for (int r=0;r<4;r++) vmax = fmaxf(vmax, o[r]);
        }
        vmax = fmaxf(vmax, __shfl_xor(vmax, 16));
        vmax = fmaxf(vmax, __shfl_xor(vmax, 32));
        if (q == 0){
            int col = nt*16 + ln;
            pooled[(long)node*160 + col] = vmax + fb[col];
        }
    }
}

// ============================ host ============================
extern "C" void kernel_launch(void* const* d_in, const int* in_sizes, int n_in,
                              void* d_out, int out_size, void* d_ws, size_t ws_size,
                              hipStream_t stream)
{
    const float* X       = (const float*)d_in[0];
    const int*   in_idx  = (const int*)  d_in[1];
    const int*   out_idx = (const int*)  d_in[2];
    const float* iWq     = (const float*)d_in[3];
    const float* iWk     = (const float*)d_in[4];
    const float* iWv     = (const float*)d_in[5];
    const float* i_in_w  = (const float*)d_in[6];
    const float* i_in_b  = (const float*)d_in[7];
    const float* i_out_w = (const float*)d_in[8];
    const float* i_out_b = (const float*)d_in[9];
    const float* oWq     = (const float*)d_in[10];
    const float* oWk     = (const float*)d_in[11];
    const float* oWv     = (const float*)d_in[12];
    const float* o_in_w  = (const float*)d_in[13];
    const float* o_in_b  = (const float*)d_in[14];
    const float* o_out_w = (const float*)d_in[15];
    const float* o_out_b = (const float*)d_in[16];
    const float* f_in_w  = (const float*)d_in[17];
    const float* f_in_b  = (const float*)d_in[18];
    const float* f_out_w = (const float*)d_in[19];
    const float* f_out_b = (const float*)d_in[20];
    const float* lin_w   = (const float*)d_in[21];
    const float* lin_b   = (const float*)d_in[22];

    float* ws = (float*)d_ws;
    float* pooled = ws;                           // 32768*160 fp32
    float* c_i    = pooled + 5242880;             // 480 (folded)
    float* c_o    = c_i + 480;
    float* cvt_i  = c_o + 480;                    // 480 raw
    float* cvt_o  = cvt_i + 480;
    float* Hvt_i  = cvt_o + 480;                  // 160x160 fp32
    float* Hvt_o  = Hvt_i + 25600;
    ushort* ub    = (ushort*)(Hvt_o + 25600);
    ushort* Xb    = ub;                           // 32768*160 bf16
    ushort* XPb_i = Xb + 5242880;                 // 32768*480 bf16
    ushort* XPb_o = XPb_i + 15728640;
    ushort* Wci_h = XPb_o + 15728640;             // 76800 each
    ushort* Wco_h = Wci_h + 76800;
    ushort* Hi_h  = Wco_h + 76800;
    ushort* Ho_h  = Hi_h  + 76800;
    ushort* li_h  = Ho_h  + 76800;                // 25600 each
    ushort* li_l  = li_h  + 25600;
    ushort* sb_us = li_l + 25600;
    const unsigned long long fixed = 23825280ULL; // floats (5296000 + 37058560/2)

    size_t avail = ws_size / 4;
    int ns = 32768;
    while (ns > 64 && fixed + 10240ULL*ns > avail) ns >>= 1;

    ushort* O_i = sb_us;                          // ns*16*160
    ushort* O_o = O_i + (size_t)2560*ns;
    ushort* FQi = O_o + (size_t)2560*ns;          // ns*16*480
    ushort* FQo = FQi + (size_t)7680*ns;

    prep_combined_bf<<<300,NTH,0,stream>>>(iWq,iWk,iWv,i_in_w, Wci_h);
    prep_combined_bf<<<300,NTH,0,stream>>>(oWq,oWk,oWv,o_in_w, Wco_h);
    prep_H_split<<<300,NTH,0,stream>>>(f_in_w, i_out_w, Hi_h, Hvt_i);
    prep_H_split<<<300,NTH,0,stream>>>(f_in_w, o_out_w, Ho_h, Hvt_o);
    prep_H_fold<<<100,NTH,0,stream>>>(f_out_w, Hvt_i, Hi_h);
    prep_H_fold<<<100,NTH,0,stream>>>(f_out_w, Hvt_o, Ho_h);
    prep_cvec<<<2,NTH,0,stream>>>(f_in_w, i_out_b, f_in_b, cvt_i);
    prep_cvec<<<2,NTH,0,stream>>>(f_in_w, o_out_b, f_in_b, cvt_o);
    prep_cvec_fold<<<2,NTH,0,stream>>>(f_out_w, cvt_i, c_i);
    prep_cvec_fold<<<2,NTH,0,stream>>>(f_out_w, cvt_o, c_o);
    prep_conv_bf2<<<100,NTH,0,stream>>>(lin_w, li_h, li_l, 25600);
    prep_conv_bf1<<<20480,NTH,0,stream>>>(X, Xb, 5242880);

    // XP = Xb @ Wc^T + in_b  -> bf16 (both layers via z)
    dim3 g1(256, 3, 2);
    gemm_bf<<<g1,NTH,0,stream>>>(Xb, Xb, Wci_h, Wco_h, i_in_b, o_in_b,
                                 XPb_i, XPb_o, 480);

    int S = 32768 / ns;
    for (int s=0;s<S;s++){
        int base = s*ns;
        dim3 ga(ns, 2);
        attn_layer_mfma<<<ga,64,0,stream>>>(XPb_i, XPb_o, in_idx, out_idx, O_i, O_o, base);
        dim3 g3(ns/8, 3, 2);
        gemm_bf<<<g3,NTH,0,stream>>>(O_i, O_o, Hi_h, Ho_h, c_i, c_o, FQi, FQo, 480);
        attn_final_pool<<<ns,64,0,stream>>>(FQi, FQo, f_out_b, pooled, base);
    }

    // out = ELU(pooled @ lin_w^T + lin_b)  fp32, split-x3
    dim3 g6(256, 1);
    gemm_mfma_lin<<<g6,NTH,0,stream>>>(pooled, li_h, li_l, lin_b, (float*)d_out, 160);
}